// Round 4
// baseline (855.857 us; speedup 1.0000x reference)
//
#include <hip/hip_runtime.h>
#include <math.h>

// Problem constants
#define B 1024
#define N 100000
#define D 512
#define H 96
#define F 7
#define K 16
#define HF (H*F)            // 672

// GEMM tiling (gmax pass)
#define QT 128              // queries per block
#define KT 128              // keys per block
#define NKT 784             // key tiles (784*128 = 100352)
#define NPAD (NKT*KT)       // 100352 (kb padded with zero rows)

// group-max pruning
#define GQ 16               // keys per group (N = 6250*16 exactly; 22 pad groups)
#define NG (NPAD/GQ)        // 6272 groups per query
#define SELG 32             // groups selected (2x margin over the exact-16 bound:
                            // bf16-filter vs fp32-final noise cannot evict a true
                            // top-16 element without >=17 simultaneous decoys)
#define CAND (SELG*GQ)      // 512 gathered candidates -> two per thread

typedef __attribute__((ext_vector_type(8))) short shortx8;   // 8 bf16 (4 VGPRs)
typedef __attribute__((ext_vector_type(4))) float floatx4;   // MFMA accumulator

__device__ __forceinline__ unsigned short f2bf(float f) {    // RTN-even fp32->bf16
    unsigned int u = __float_as_uint(f);
    u += 0x7FFF + ((u >> 16) & 1);
    return (unsigned short)(u >> 16);
}

// async 16B/lane global->LDS; LDS dest is wave-uniform base + lane*16
#define ASYNC16(g, l) __builtin_amdgcn_global_load_lds( \
    (__attribute__((address_space(1))) void*)(g), \
    (__attribute__((address_space(3))) void*)(l), 16, 0, 0)

// ---------------- prep: normalize queries (fp32 + bf16 copies) ----------------
__global__ void prep_q(const float* __restrict__ q, float* __restrict__ qn,
                       unsigned short* __restrict__ qb) {
    int w = (blockIdx.x * blockDim.x + threadIdx.x) >> 6;   // one wave per row
    int l = threadIdx.x & 63;
    if (w >= B) return;
    const float4* row = (const float4*)(q + (size_t)w * D);
    float4 a = row[l], b = row[l + 64];
    float ss = a.x*a.x + a.y*a.y + a.z*a.z + a.w*a.w
             + b.x*b.x + b.y*b.y + b.z*b.z + b.w*b.w;
#pragma unroll
    for (int off = 32; off; off >>= 1) ss += __shfl_xor(ss, off);
    float nrm = fmaxf(sqrtf(ss), 1e-12f);
    a.x /= nrm; a.y /= nrm; a.z /= nrm; a.w /= nrm;
    b.x /= nrm; b.y /= nrm; b.z /= nrm; b.w /= nrm;
    float4* o = (float4*)(qn + (size_t)w * D);
    o[l] = a; o[l + 64] = b;
    unsigned short* ob = qb + (size_t)w * D;
    *(ushort4*)(ob + 4*l)       = make_ushort4(f2bf(a.x), f2bf(a.y), f2bf(a.z), f2bf(a.w));
    *(ushort4*)(ob + 256 + 4*l) = make_ushort4(f2bf(b.x), f2bf(b.y), f2bf(b.z), f2bf(b.w));
}

// ---------------- prep: kscale fp32 + pre-scaled bf16 keys (zero-padded) ------
__global__ void prep_k(const float* __restrict__ keys, const int* __restrict__ ts,
                       const int* __restrict__ gstep, float* __restrict__ kscale,
                       unsigned short* __restrict__ kb) {
    int w = (blockIdx.x * blockDim.x + threadIdx.x) >> 6;   // one wave per row
    int l = threadIdx.x & 63;
    if (w >= NPAD) return;
    unsigned short* dst = kb + (size_t)w * D;
    if (w >= N) {                                           // zero pad rows -> score 0
        *(ushort4*)(dst + 4*l)       = make_ushort4(0,0,0,0);
        *(ushort4*)(dst + 256 + 4*l) = make_ushort4(0,0,0,0);
        return;
    }
    const float4* row = (const float4*)(keys + (size_t)w * D);
    float4 a = row[l], b = row[l + 64];
    float ss = a.x*a.x + a.y*a.y + a.z*a.z + a.w*a.w
             + b.x*b.x + b.y*b.y + b.z*b.z + b.w*b.w;
#pragma unroll
    for (int off = 32; off; off >>= 1) ss += __shfl_xor(ss, off);
    float age = (float)(gstep[0] - ts[w]);
    float sc = powf(0.995f, age) / fmaxf(sqrtf(ss), 1e-12f);
    if (l == 0) kscale[w] = sc;
    *(ushort4*)(dst + 4*l)       = make_ushort4(f2bf(a.x*sc), f2bf(a.y*sc), f2bf(a.z*sc), f2bf(a.w*sc));
    *(ushort4*)(dst + 256 + 4*l) = make_ushort4(f2bf(b.x*sc), f2bf(b.y*sc), f2bf(b.z*sc), f2bf(b.w*sc));
}

// ---------------- pass 1: bf16 MFMA GEMM -> per-(query, 16-key-group) max ----
// m97 structure: 128x128 tile, BK=32, 2 barriers/K-step, 16 K-steps. Epilogue
// folds each 16-col MFMA accumulator block over its 16 m-lanes -> group max,
// stored as one float4 (4 consecutive group cols per wave).
__global__ __launch_bounds__(256, 3)
void gmax_k(const unsigned short* __restrict__ qb, const unsigned short* __restrict__ kb,
            float* __restrict__ gmax) {
    __shared__ __align__(16) unsigned short As[QT * 32];   // 8 KB
    __shared__ __align__(16) unsigned short Bs[KT * 32];   // 8 KB

    const int t = threadIdx.x;
    const int w = t >> 6, l = t & 63;
    const int qbase = blockIdx.x * QT;
    const int kbase = blockIdx.y * KT;
    const int m = l & 15, quad = l >> 4;
    const int wq = w & 1, wk = w >> 1;

    // staging: each ASYNC16 moves 1KB = 16 rows x 64B; wave w owns rows w*32..+31
    const int srow = l >> 2;
    const int scol = (l & 3) * 8;
    const unsigned short* gA0 = qb + (size_t)(qbase + w*32 + srow) * D + scol;
    const unsigned short* gA1 = gA0 + (size_t)16 * D;
    const unsigned short* gB0 = kb + (size_t)(kbase + w*32 + srow) * D + scol;
    const unsigned short* gB1 = gB0 + (size_t)16 * D;
    unsigned short* lA0 = As + (w*32) * 32;      // wave-uniform LDS bases
    unsigned short* lA1 = As + (w*32 + 16) * 32;
    unsigned short* lB0 = Bs + (w*32) * 32;
    unsigned short* lB1 = Bs + (w*32 + 16) * 32;

    // fragment read bases (A-operand layout: row=lane&15, k=quad*8+j)
    const unsigned short* aBase = As + (size_t)(wq*64 + m) * 32 + quad*8;
    const unsigned short* bBase = Bs + (size_t)(wk*64 + m) * 32 + quad*8;

    floatx4 acc[4][4];
#pragma unroll
    for (int i = 0; i < 4; ++i)
#pragma unroll
        for (int j = 0; j < 4; ++j) acc[i][j] = (floatx4){0.f, 0.f, 0.f, 0.f};

    for (int ds = 0; ds < D/32; ++ds) {
        ASYNC16(gA0 + ds*32, lA0);
        ASYNC16(gA1 + ds*32, lA1);
        ASYNC16(gB0 + ds*32, lB0);
        ASYNC16(gB1 + ds*32, lB1);
        __syncthreads();                         // drains vmcnt before barrier
        shortx8 af[4], bf[4];
#pragma unroll
        for (int i = 0; i < 4; ++i) af[i] = *(const shortx8*)(aBase + i*512);
#pragma unroll
        for (int j = 0; j < 4; ++j) bf[j] = *(const shortx8*)(bBase + j*512);
#pragma unroll
        for (int i = 0; i < 4; ++i)
#pragma unroll
            for (int j = 0; j < 4; ++j)
                acc[i][j] = __builtin_amdgcn_mfma_f32_16x16x32_bf16(
                    af[i], bf[j], acc[i][j], 0, 0, 0);
        __syncthreads();                         // reads done before next stage
    }

    // epilogue: C layout col(key)=lane&15, row(query)=quad*4+r.
    // each kk block (16 cols) is one key-group; fold over the 16 m-lanes.
    const int gcol = blockIdx.y * 8 + wk * 4;    // 4 consecutive group cols/wave
#pragma unroll
    for (int qt = 0; qt < 4; ++qt)
#pragma unroll
        for (int r = 0; r < 4; ++r) {
            float v0 = acc[qt][0][r], v1 = acc[qt][1][r];
            float v2 = acc[qt][2][r], v3 = acc[qt][3][r];
#pragma unroll
            for (int off = 1; off < 16; off <<= 1) {     // fold 16 m-lanes
                v0 = fmaxf(v0, __shfl_xor(v0, off));
                v1 = fmaxf(v1, __shfl_xor(v1, off));
                v2 = fmaxf(v2, __shfl_xor(v2, off));
                v3 = fmaxf(v3, __shfl_xor(v3, off));
            }
            if (m == 0) {
                size_t row = (size_t)(qbase + wq*64 + qt*16 + quad*4 + r);
                *(float4*)(gmax + row * NG + gcol) = make_float4(v0, v1, v2, v3);
            }
        }
}

// ---------------- pass 2: per-query select + exact fp32 rescore + output -----
// top-32 groups by (bf16 max desc, idx asc) contain the fp32 top-16 elements
// with overwhelming margin. 512 candidates -> two per thread, exact fp32 dots
// (no shuffles, no barriers), then single-wave top-16 + softmax + output.
__global__ __launch_bounds__(256)
void select_out(const float* __restrict__ gmax, const float* __restrict__ qn,
                const float* __restrict__ keys, const float* __restrict__ kscale,
                const float* __restrict__ values, float* __restrict__ out) {
    int b = blockIdx.x, t = threadIdx.x;
    __shared__ float sG[NG];                 // 25 KB group maxes
    __shared__ float qrow[D];                // fp32 normalized q (2 KB)
    __shared__ int   gSel[SELG];
    __shared__ float eS[CAND];               // exact fp32 candidate scores
    __shared__ int   eI[CAND];               // global key indices
    __shared__ float rS[4]; __shared__ int rP[4];
    __shared__ float selS[K]; __shared__ int selI[K];
    __shared__ float wgt[K]; __shared__ int wIdx[K];

    // vectorized loads of group maxes + query row
    {
        const float4* gs = (const float4*)(gmax + (size_t)b * NG);
        float4* gd = (float4*)sG;
        for (int i = t; i < NG/4; i += 256) gd[i] = gs[i];
        const float4* qs = (const float4*)(qn + (size_t)b * D);
        if (t < D/4) ((float4*)qrow)[t] = qs[t];
    }
    __syncthreads();

    int lane = t & 63, w = t >> 6;

    // ---- top-32 groups (max desc, group idx asc) ----
    for (int r = 0; r < SELG; ++r) {
        float best = -INFINITY; int bp = 0x7fffffff;
        for (int i = t; i < NG; i += 256) {
            float v = sG[i];
            if (v > best || (v == best && i < bp)) { best = v; bp = i; }
        }
#pragma unroll
        for (int off = 32; off; off >>= 1) {
            float ob = __shfl_xor(best, off);
            int op = __shfl_xor(bp, off);
            if (ob > best || (ob == best && op < bp)) { best = ob; bp = op; }
        }
        if (lane == 0) { rS[w] = best; rP[w] = bp; }
        __syncthreads();
        if (t == 0) {
            float bb = rS[0]; int bbp = rP[0];
            for (int j = 1; j < 4; ++j)
                if (rS[j] > bb || (rS[j] == bb && rP[j] < bbp)) { bb = rS[j]; bbp = rP[j]; }
            gSel[r] = bbp; sG[bbp] = -INFINITY;
        }
        __syncthreads();
    }

    // ---- exact fp32 rescore, two candidates per thread (512 = 2*blockDim) ----
    {
        int ga = gSel[t >> 4];                   // candidate t
        int gb = gSel[(t >> 4) + 16];            // candidate t + 256
        int ia = ga * GQ + (t & 15);
        int ib = gb * GQ + (t & 15);
        bool va = ia < N, vb = ib < N;
        const float4* ka = (const float4*)(keys + (size_t)(va ? ia : 0) * D);
        const float4* kb4 = (const float4*)(keys + (size_t)(vb ? ib : 0) * D);
        const float4* qs = (const float4*)qrow;
        float a0 = 0.f, a1 = 0.f, a2 = 0.f, a3 = 0.f;
        float b0 = 0.f, b1 = 0.f, b2 = 0.f, b3 = 0.f;
#pragma unroll 8
        for (int d = 0; d < D/4; ++d) {
            float4 qv = qs[d];
            float4 kva = ka[d];
            float4 kvb = kb4[d];
            a0 = fmaf(qv.x, kva.x, a0);
            a1 = fmaf(qv.y, kva.y, a1);
            a2 = fmaf(qv.z, kva.z, a2);
            a3 = fmaf(qv.w, kva.w, a3);
            b0 = fmaf(qv.x, kvb.x, b0);
            b1 = fmaf(qv.y, kvb.y, b1);
            b2 = fmaf(qv.z, kvb.z, b2);
            b3 = fmaf(qv.w, kvb.w, b3);
        }
        float pa = (a0 + a1) + (a2 + a3);
        float pb = (b0 + b1) + (b2 + b3);
        eS[t]       = va ? pa * kscale[ia] : -INFINITY;
        eI[t]       = ia;
        eS[t + 256] = vb ? pb * kscale[ib] : -INFINITY;
        eI[t + 256] = ib;
    }
    __syncthreads();

    // ---- top-16 of 512 on wave 0 (lane holds 8 in regs; barrier-free) ----
    if (w == 0) {
        float v[8]; int idx[8];
#pragma unroll
        for (int j = 0; j < 8; ++j) { v[j] = eS[lane + 64*j]; idx[j] = eI[lane + 64*j]; }
#pragma unroll
        for (int r = 0; r < K; ++r) {
            float bv = v[0]; int bi = idx[0];
#pragma unroll
            for (int j = 1; j < 8; ++j)
                if (v[j] > bv || (v[j] == bv && idx[j] < bi)) { bv = v[j]; bi = idx[j]; }
#pragma unroll
            for (int off = 32; off; off >>= 1) {
                float ov = __shfl_xor(bv, off);
                int oi = __shfl_xor(bi, off);
                if (ov > bv || (ov == bv && oi < bi)) { bv = ov; bi = oi; }
            }
            if (lane == 0) { selS[r] = bv; selI[r] = bi; }
            // invalidate winner (candidate indices are unique across the 512)
#pragma unroll
            for (int j = 0; j < 8; ++j)
                if (idx[j] == bi) v[j] = -INFINITY;
        }
        if (lane == 0) {                         // softmax weights (scores desc)
            float y[K], e[K];
            for (int k = 0; k < K; ++k) y[k] = selS[k] / 0.1f;
            float ymax = y[0];
            float Z = 0.f;
            for (int k = 0; k < K; ++k) { e[k] = expf(y[k] - ymax); Z += e[k]; }
            float Z2 = 0.f;
            for (int k = 0; k < K; ++k) {
                float ww = e[k] / Z;
                if (!(selS[k] >= 0.0f)) ww = 0.f;
                e[k] = ww; Z2 += ww;
            }
            for (int k = 0; k < K; ++k) { wgt[k] = e[k] / (Z2 + 1e-8f); wIdx[k] = selI[k]; }
        }
    }
    __syncthreads();

    // ---- output: 168 float4 slots, 16 coalesced row-gathers each ----
    if (t < HF/4) {
        float4 o = make_float4(0.f, 0.f, 0.f, 0.f);
#pragma unroll
        for (int k = 0; k < K; ++k) {
            const float4* vr = (const float4*)(values + (size_t)wIdx[k] * HF);
            float4 v = vr[t];
            float ww = wgt[k];
            o.x = fmaf(ww, v.x, o.x);
            o.y = fmaf(ww, v.y, o.y);
            o.z = fmaf(ww, v.z, o.z);
            o.w = fmaf(ww, v.w, o.w);
        }
        ((float4*)(out + (size_t)b * HF))[t] = o;
    }
}

extern "C" void kernel_launch(void* const* d_in, const int* in_sizes, int n_in,
                              void* d_out, int out_size, void* d_ws, size_t ws_size,
                              hipStream_t stream) {
    const float* query  = (const float*)d_in[0];
    const float* keys   = (const float*)d_in[1];
    const float* values = (const float*)d_in[2];
    const int*   ts     = (const int*)d_in[3];
    const int*   gstep  = (const int*)d_in[4];
    float* out = (float*)d_out;

    // workspace carve-out (256B aligned); total ~132 MB
    char* p = (char*)d_ws;
    size_t o = 0;
    auto alloc = [&](size_t bytes) { char* r = p + o; o = (o + bytes + 255) & ~(size_t)255; return r; };
    float*          qn     = (float*)alloc((size_t)B * D * 4);
    unsigned short* qb     = (unsigned short*)alloc((size_t)B * D * 2);
    float*          kscale = (float*)alloc((size_t)N * 4);
    unsigned short* kb     = (unsigned short*)alloc((size_t)NPAD * D * 2);
    float*          gmax   = (float*)alloc((size_t)B * NG * 4);

    prep_q<<<B / 4, 256, 0, stream>>>(query, qn, qb);
    prep_k<<<NPAD / 4, 256, 0, stream>>>(keys, ts, gstep, kscale, kb);
    dim3 g2(B / QT, NKT);
    gmax_k<<<g2, 256, 0, stream>>>(qb, kb, gmax);
    select_out<<<B, 256, 0, stream>>>(gmax, qn, keys, kscale, values, out);
}